// Round 4
// baseline (188.806 us; speedup 1.0000x reference)
//
#include <hip/hip_runtime.h>

#define N_NODES   100000
#define N_EDGES   1600000
#define N_GRAPHS  128
#define HIDDEN    128
#define N_CLASSES 10

#define BSH   8                   // bucket = 256 nodes
#define BSZ   256
#define NBUCK 391                 // ceil(100000/256)
#define NPAD  (NBUCK * BSZ)       // 100096 padded node count
#define NBIN  512                 // histogram bins (>= NBUCK)
#define CAP   8192                // mean fill 4096, huge headroom
#define PCH   4096                // edges per partition block
#define PTH   512                 // partition threads
#define PIT   (PCH / PTH)         // 8 edges cached per thread
#define SPLIT 4                   // sub-blocks per bucket in gather kernels

typedef unsigned int   uint;
typedef unsigned short ushort;

// ---- 512-wide exclusive scan: wave shfl scan + tiny cross-wave fixup (2 syncs)
__device__ __forceinline__ uint scan_excl_512(uint v, int t, uint* wtmp) {
    uint lane = (uint)(t & 63);
    uint incl = v;
    #pragma unroll
    for (int off = 1; off < 64; off <<= 1) {
        uint up = __shfl_up(incl, off, 64);
        if (lane >= (uint)off) incl += up;
    }
    if (lane == 63) wtmp[t >> 6] = incl;
    __syncthreads();
    uint wo = 0;
    int w = t >> 6;
    #pragma unroll
    for (int k = 0; k < 7; ++k) wo += (k < w) ? wtmp[k] : 0u;
    __syncthreads();                 // wtmp reusable by next call
    return incl + wo - v;
}

// -------- partition (verified round-3 kernel, unchanged) ---------------------
__global__ __launch_bounds__(PTH)
void k_part(const int* __restrict__ src, const int* __restrict__ dst,
            uint* __restrict__ bcur1, uint* __restrict__ bcur2,
            uint* __restrict__ tmp1, ushort* __restrict__ tmp2, int nE) {
    __shared__ uint   hist[NBIN], lcur[NBIN], base[NBIN];
    __shared__ uint   wtmp[8];
    __shared__ uint   stag4[PCH];        // 16 KB
    __shared__ ushort stagB[PCH];        // 8 KB (phase 1 only)
    int t = threadIdx.x;
    int e0 = blockIdx.x * PCH;
    int e1 = min(e0 + PCH, nE);
    int cntE = e1 - e0;

    int sv[PIT], dv[PIT];
    // ---------------- phase 1: dst ----------------
    hist[t] = 0;                         // NBIN == PTH
    __syncthreads();
    #pragma unroll
    for (int m = 0; m < PIT; ++m) {
        int e = e0 + t + m * PTH;
        if (e < e1) {
            sv[m] = src[e]; dv[m] = dst[e];
            atomicAdd(&hist[dv[m] >> BSH], 1u);
        }
    }
    __syncthreads();
    uint v = hist[t];
    uint excl = scan_excl_512(v, t, wtmp);
    lcur[t] = excl;
    if (v > 0) { uint g = atomicAdd(&bcur1[t], v); base[t] = (uint)t * CAP + g - excl; }
    __syncthreads();
    #pragma unroll
    for (int m = 0; m < PIT; ++m) {
        int e = e0 + t + m * PTH;
        if (e < e1) {
            int d = dv[m], s = sv[m];
            int b = d >> BSH;
            uint p = atomicAdd(&lcur[b], 1u);
            stag4[p] = ((uint)(d & (BSZ - 1)) << 17) | (uint)s;
            stagB[p] = (ushort)b;
        }
    }
    __syncthreads();
    for (int i = t; i < cntE; i += PTH) {
        uint b = stagB[i];
        uint a = base[b] + (uint)i;
        if (a < (b + 1u) * CAP) tmp1[a] = stag4[i];
    }
    __syncthreads();

    // ---------------- phase 2: src ----------------
    hist[t] = 0;
    __syncthreads();
    #pragma unroll
    for (int m = 0; m < PIT; ++m) {
        int e = e0 + t + m * PTH;
        if (e < e1) atomicAdd(&hist[sv[m] >> BSH], 1u);
    }
    __syncthreads();
    v = hist[t];
    excl = scan_excl_512(v, t, wtmp);
    lcur[t] = excl;
    if (v > 0) { uint g = atomicAdd(&bcur2[t], v); base[t] = (uint)t * CAP + g - excl; }
    __syncthreads();
    #pragma unroll
    for (int m = 0; m < PIT; ++m) {
        int e = e0 + t + m * PTH;
        if (e < e1) {
            int s = sv[m];
            uint p = atomicAdd(&lcur[s >> BSH], 1u);
            stag4[p] = (uint)s;
        }
    }
    __syncthreads();
    for (int i = t; i < cntE; i += PTH) {
        uint s = stag4[i];
        uint b = s >> BSH;
        uint a = base[b] + (uint)i;
        if (a < (b + 1u) * CAP) tmp2[a] = (ushort)(s & (BSZ - 1));
    }
}

// ------- degrees: (bucket, quarter) blocks, LDS partial + coalesced atomic merge
__global__ __launch_bounds__(256)
void k_cnt4(const uint* __restrict__ bcur1, const uint* __restrict__ tmp1,
            const uint* __restrict__ bcur2, const ushort* __restrict__ tmp2,
            uint* __restrict__ cin, uint* __restrict__ cout) {
    __shared__ uint lin[BSZ], lout[BSZ];
    int b = blockIdx.x >> 2, q = blockIdx.x & 3;
    int t = threadIdx.x;
    lin[t] = 0; lout[t] = 0;
    __syncthreads();
    uint f1 = min(bcur1[b], (uint)CAP);
    uint lo = f1 * (uint)q / 4u, hi = f1 * (uint)(q + 1) / 4u;
    const uint* tp1 = tmp1 + (size_t)b * CAP;
    uint i = lo + t;
    for (; i + 768u < hi; i += 1024u) {
        uint a0 = tp1[i], a1 = tp1[i + 256], a2 = tp1[i + 512], a3 = tp1[i + 768];
        atomicAdd(&lin[a0 >> 17], 1u); atomicAdd(&lin[a1 >> 17], 1u);
        atomicAdd(&lin[a2 >> 17], 1u); atomicAdd(&lin[a3 >> 17], 1u);
    }
    for (; i < hi; i += 256u) atomicAdd(&lin[tp1[i] >> 17], 1u);

    uint f2 = min(bcur2[b], (uint)CAP);
    uint lo2 = f2 * (uint)q / 4u, hi2 = f2 * (uint)(q + 1) / 4u;
    const ushort* tp2 = tmp2 + (size_t)b * CAP;
    i = lo2 + t;
    for (; i + 768u < hi2; i += 1024u) {
        uint a0 = tp2[i], a1 = tp2[i + 256], a2 = tp2[i + 512], a3 = tp2[i + 768];
        atomicAdd(&lout[a0], 1u); atomicAdd(&lout[a1], 1u);
        atomicAdd(&lout[a2], 1u); atomicAdd(&lout[a3], 1u);
    }
    for (; i < hi2; i += 256u) atomicAdd(&lout[tp2[i]], 1u);
    __syncthreads();
    int n = b * BSZ + t;
    if (lin[t])  atomicAdd(&cin[n],  lin[t]);
    if (lout[t]) atomicAdd(&cout[n], lout[t]);
}

// ------- node pass 1: ns/hs0/ndv from degrees; zero aggC; U/V table (blocks<129)
__global__ __launch_bounds__(256)
void k_node1(const uint* __restrict__ cin, const uint* __restrict__ cout,
             const float* __restrict__ W1, const float* __restrict__ b1,
             const float* __restrict__ W2,
             float* __restrict__ ns, float* __restrict__ hs0, float* __restrict__ ndv,
             float* __restrict__ aggC, float* __restrict__ U, float* __restrict__ V) {
    __shared__ float sts[128];
    int b = blockIdx.x, t = threadIdx.x;
    if (b < 129) {                    // block-uniform branch: syncs legal
        if (t < 128) {
            float w = W1[t], bb = b1[t];
            sts[t] = (w != 0.0f) ? (-bb / w) : 1e30f;
        }
        __syncthreads();
        for (int k = 2; k <= 128; k <<= 1) {
            for (int j = k >> 1; j > 0; j >>= 1) {
                if (t < 128) {
                    int ixj = t ^ j;
                    if (ixj > t) {
                        float a = sts[t], bb = sts[ixj];
                        bool up = ((t & k) == 0);
                        if (up ? (a > bb) : (a < bb)) { sts[t] = bb; sts[ixj] = a; }
                    }
                }
                __syncthreads();
            }
        }
        if (t < 128) {                // segment-table row, unconditional W2 loads
            int sg = b;
            float a_rep;
            if (sg == 0)        a_rep = sts[0]   - 1.0f;
            else if (sg == 128) a_rep = sts[127] + 1.0f;
            else                a_rep = 0.5f * (sts[sg - 1] + sts[sg]);
            float u = 0.0f, vv = 0.0f;
            #pragma unroll 8
            for (int j = 0; j < 128; ++j) {
                float w  = W1[j], bb = b1[j];
                float w2 = W2[j * HIDDEN + t];
                bool on  = (a_rep * w + bb > 0.0f);
                u  += on ? w  * w2 : 0.0f;
                vv += on ? bb * w2 : 0.0f;
            }
            U[sg * HIDDEN + t] = u;
            V[sg * HIDDEN + t] = vv;
        }
    }
    int n = b * 256 + t;              // n < NPAD always (391*256)
    uint ci = cin[n];
    float nsv = rsqrtf(fmaxf((float)cout[n], 1.0f));
    ns[n]   = nsv;
    hs0[n]  = (float)ci * nsv;        // h0 = indeg; hs0 = h0*norm_src
    ndv[n]  = rsqrtf(fmaxf((float)ci, 1.0f));
    aggC[n] = 0.0f;
}

// ------- conv1 aggregation: (bucket, quarter), LDS partial + coalesced merge
__global__ __launch_bounds__(256)
void k_agg1(const uint* __restrict__ bcur1, const uint* __restrict__ tmp1,
            const float* __restrict__ hs0, float* __restrict__ aggC) {
    __shared__ float agg[BSZ];
    int b = blockIdx.x >> 2, q = blockIdx.x & 3;
    int t = threadIdx.x;
    agg[t] = 0.0f;
    __syncthreads();
    uint f1 = min(bcur1[b], (uint)CAP);
    uint lo = f1 * (uint)q / 4u, hi = f1 * (uint)(q + 1) / 4u;
    const uint* tp1 = tmp1 + (size_t)b * CAP;
    uint i = lo + t;
    for (; i + 768u < hi; i += 1024u) {
        uint e0 = tp1[i], e1 = tp1[i + 256], e2 = tp1[i + 512], e3 = tp1[i + 768];
        float h0 = hs0[e0 & 0x1FFFFu], h1 = hs0[e1 & 0x1FFFFu];
        float h2 = hs0[e2 & 0x1FFFFu], h3 = hs0[e3 & 0x1FFFFu];
        atomicAdd(&agg[e0 >> 17], h0); atomicAdd(&agg[e1 >> 17], h1);
        atomicAdd(&agg[e2 >> 17], h2); atomicAdd(&agg[e3 >> 17], h3);
    }
    for (; i < hi; i += 256u) {
        uint e = tp1[i];
        atomicAdd(&agg[e >> 17], hs0[e & 0x1FFFFu]);
    }
    __syncthreads();
    if (agg[t] != 0.0f) atomicAdd(&aggC[b * BSZ + t], agg[t]);
}

// ------- node pass 2: info from merged aggC; init conv2 accumulators
__global__ __launch_bounds__(256)
void k_node2(const float* __restrict__ aggC, const float* __restrict__ ns,
             const float* __restrict__ ndv,
             const float* __restrict__ W1, const float* __restrict__ b1,
             float4* __restrict__ info, float* __restrict__ aggA,
             float* __restrict__ aggB, uint* __restrict__ aggMn,
             uint* __restrict__ aggMx) {
    __shared__ float stu[128];
    int t = threadIdx.x;
    if (t < 128) {
        float w = W1[t], bb = b1[t];
        stu[t] = (w != 0.0f) ? (-bb / w) : 1e30f;
    }
    __syncthreads();
    int n = blockIdx.x * 256 + t;     // n < NPAD always
    float nd = ndv[n];
    float av = aggC[n] * nd;
    int sgp = 0;
    #pragma unroll 16
    for (int q = 0; q < 128; ++q) sgp += (stu[q] < av) ? 1 : 0;
    float nsv = ns[n];
    info[n] = make_float4(nsv * av, nsv, __int_as_float(sgp), nd);
    aggA[n] = 0.0f; aggB[n] = 0.0f; aggMn[n] = 255u; aggMx[n] = 0u;
}

// ------- conv2 aggregation: (bucket, quarter), LDS partial + coalesced merge
__global__ __launch_bounds__(256)
void k_agg2(const uint* __restrict__ bcur1, const uint* __restrict__ tmp1,
            const float4* __restrict__ info,
            float* __restrict__ aggA, float* __restrict__ aggB,
            uint* __restrict__ aggMn, uint* __restrict__ aggMx) {
    __shared__ float lA[BSZ], lB[BSZ];
    __shared__ uint  lmn[BSZ], lmx[BSZ];
    int b = blockIdx.x >> 2, q = blockIdx.x & 3;
    int t = threadIdx.x;
    lA[t] = 0.0f; lB[t] = 0.0f; lmn[t] = 255u; lmx[t] = 0u;
    __syncthreads();
    uint f1 = min(bcur1[b], (uint)CAP);
    uint lo = f1 * (uint)q / 4u, hi = f1 * (uint)(q + 1) / 4u;
    const uint* tp1 = tmp1 + (size_t)b * CAP;
    uint i = lo + t;
    for (; i + 768u < hi; i += 1024u) {
        uint e0 = tp1[i], e1 = tp1[i + 256], e2 = tp1[i + 512], e3 = tp1[i + 768];
        float4 n0 = info[e0 & 0x1FFFFu];
        float4 n1 = info[e1 & 0x1FFFFu];
        float4 n2 = info[e2 & 0x1FFFFu];
        float4 n3 = info[e3 & 0x1FFFFu];
        uint d0 = e0 >> 17, d1 = e1 >> 17, d2 = e2 >> 17, d3 = e3 >> 17;
        atomicAdd(&lA[d0], n0.x); atomicAdd(&lB[d0], n0.y);
        atomicAdd(&lA[d1], n1.x); atomicAdd(&lB[d1], n1.y);
        atomicAdd(&lA[d2], n2.x); atomicAdd(&lB[d2], n2.y);
        atomicAdd(&lA[d3], n3.x); atomicAdd(&lB[d3], n3.y);
        uint s0 = (uint)__float_as_int(n0.z), s1 = (uint)__float_as_int(n1.z);
        uint s2 = (uint)__float_as_int(n2.z), s3 = (uint)__float_as_int(n3.z);
        atomicMin(&lmn[d0], s0); atomicMax(&lmx[d0], s0);
        atomicMin(&lmn[d1], s1); atomicMax(&lmx[d1], s1);
        atomicMin(&lmn[d2], s2); atomicMax(&lmx[d2], s2);
        atomicMin(&lmn[d3], s3); atomicMax(&lmx[d3], s3);
    }
    for (; i < hi; i += 256u) {
        uint e = tp1[i];
        uint dl = e >> 17;
        float4 nf = info[e & 0x1FFFFu];
        atomicAdd(&lA[dl], nf.x);
        atomicAdd(&lB[dl], nf.y);
        uint sg = (uint)__float_as_int(nf.z);
        atomicMin(&lmn[dl], sg);
        atomicMax(&lmx[dl], sg);
    }
    __syncthreads();
    if (lmn[t] <= lmx[t]) {           // touched
        int n = b * BSZ + t;
        atomicAdd(&aggA[n], lA[t]);
        atomicAdd(&aggB[n], lB[t]);
        atomicMin(&aggMn[n], lmn[t]);
        atomicMax(&aggMx[n], lmx[t]);
    }
}

// ------- rows + pooling: 128 nodes/block, 2 node-lanes x 128 dims,
//         LDS graph-slot pre-merge, coalesced pool atomics.
__global__ __launch_bounds__(256)
void k_pool(const uint* __restrict__ bcur1, const uint* __restrict__ tmp1,
            const float4* __restrict__ info, const float* __restrict__ ndv,
            const float* __restrict__ aggA, const float* __restrict__ aggB,
            const uint* __restrict__ aggMn, const uint* __restrict__ aggMx,
            const float* __restrict__ U, const float* __restrict__ V,
            const int* __restrict__ graph_ids, const float* __restrict__ b2,
            float* __restrict__ pool, float* __restrict__ cnt) {
    __shared__ float psl[4][HIDDEN];
    __shared__ float csl[4];
    __shared__ uint  tfl[4];
    __shared__ int   g0s;
    int t = threadIdx.x;
    int d = t & 127, j = t >> 7;
    int nb = blockIdx.x * 128;
    if (t < 4) { csl[t] = 0.0f; tfl[t] = 0u; }
    for (int s = t; s < 4 * HIDDEN; s += 256) ((float*)psl)[s] = 0.0f;
    if (t == 0) g0s = graph_ids[nb];    // nb < N_NODES always (last block nb=99968)
    __syncthreads();
    int g0 = g0s;
    float b2d = b2[d];
    int gcur = -1; float racc = 0.0f, cl = 0.0f;
    for (int r = j; r < 128; r += 2) {
        int n = nb + r;
        if (n >= N_NODES) break;
        uint mn = aggMn[n], mx = aggMx[n];
        float acc;
        if (mn >= mx) {                 // uniform segment (or no edges: A=B=0)
            uint sg = min(mn, 128u);
            acc = aggA[n] * U[sg * HIDDEN + d] + aggB[n] * V[sg * HIDDEN + d];
        } else {                        // mixed: exact rescan of bucket edges (rare)
            acc = 0.0f;
            int bb = n >> BSH;
            uint f1 = min(bcur1[bb], (uint)CAP);
            const uint* tp1 = tmp1 + (size_t)bb * CAP;
            uint dl = (uint)(n & (BSZ - 1));
            for (uint k = 0; k < f1; ++k) {
                uint e = tp1[k];
                if ((e >> 17) == dl) {
                    float4 nf = info[e & 0x1FFFFu];
                    uint sg = (uint)__float_as_int(nf.z);
                    acc += nf.x * U[sg * HIDDEN + d] + nf.y * V[sg * HIDDEN + d];
                }
            }
        }
        float row = fmaxf(ndv[n] * acc + b2d, 0.0f);
        int g = graph_ids[n];
        if (g != gcur) {
            if (gcur >= 0) {
                int slot = gcur - g0;
                if (slot >= 0 && slot < 4) {
                    atomicAdd(&psl[slot][d], racc);
                    if (d == 0) { atomicAdd(&csl[slot], cl); tfl[slot] = 1u; }
                } else {
                    atomicAdd(&pool[gcur * HIDDEN + d], racc);
                    if (d == 0) atomicAdd(&cnt[gcur], cl);
                }
            }
            gcur = g; racc = 0.0f; cl = 0.0f;
        }
        racc += row; cl += 1.0f;
    }
    if (gcur >= 0) {
        int slot = gcur - g0;
        if (slot >= 0 && slot < 4) {
            atomicAdd(&psl[slot][d], racc);
            if (d == 0) { atomicAdd(&csl[slot], cl); tfl[slot] = 1u; }
        } else {
            atomicAdd(&pool[gcur * HIDDEN + d], racc);
            if (d == 0) atomicAdd(&cnt[gcur], cl);
        }
    }
    __syncthreads();
    #pragma unroll
    for (int s = 0; s < 4; ++s) {
        if (tfl[s]) {
            if (t < 128) atomicAdd(&pool[(g0 + s) * HIDDEN + t], psl[s][t]);
            if (t == 128) atomicAdd(&cnt[g0 + s], csl[s]);
        }
    }
}

// ----------------------------------------------- classifier head (tiny)
__global__ void k_final(const float* __restrict__ pool, const float* __restrict__ cnt,
                        const float* __restrict__ Wc, const float* __restrict__ bc,
                        float* __restrict__ out) {
    int t = blockIdx.x * blockDim.x + threadIdx.x;
    if (t >= N_GRAPHS * N_CLASSES) return;
    int g = t / N_CLASSES, c = t % N_CLASSES;
    float inv = 1.0f / fmaxf(cnt[g], 1.0f);
    float acc = bc[c];
    for (int j = 0; j < HIDDEN; ++j)
        acc += pool[g * HIDDEN + j] * inv * Wc[j * N_CLASSES + c];
    out[t] = acc;
}

extern "C" void kernel_launch(void* const* d_in, const int* in_sizes, int n_in,
                              void* d_out, int out_size, void* d_ws, size_t ws_size,
                              hipStream_t stream) {
    const int*   src       = (const int*)d_in[0];
    const int*   dst       = (const int*)d_in[1];
    const int*   graph_ids = (const int*)d_in[2];
    const float* W1        = (const float*)d_in[3];
    const float* b1        = (const float*)d_in[4];
    const float* W2        = (const float*)d_in[5];
    const float* b2        = (const float*)d_in[6];
    const float* Wc        = (const float*)d_in[7];
    const float* bc        = (const float*)d_in[8];
    float* out = (float*)d_out;

    char* ws = (char*)d_ws;
    size_t off = 0;
    auto alloc = [&](size_t elems) { void* p = ws + off; off += elems * 4; return p; };

    // --- zeroed region (single ~870KB memset) ---
    uint*  bcur1 = (uint*) alloc(NBIN);
    uint*  bcur2 = (uint*) alloc(NBIN);
    float* pool  = (float*)alloc(N_GRAPHS * HIDDEN);        // 64 KB
    float* cnt   = (float*)alloc(N_GRAPHS);
    uint*  cin   = (uint*) alloc(NPAD);                     // 400 KB
    uint*  cout  = (uint*) alloc(NPAD);                     // 400 KB
    size_t zero_bytes = off;
    // --- non-zeroed ---
    float4* info  = (float4*)alloc((size_t)NPAD * 4);       // 1.6 MB (16B-aligned)
    uint*   tmp1  = (uint*)  alloc((size_t)NBUCK * CAP);    // 12.8 MB
    ushort* tmp2  = (ushort*)alloc((size_t)NBUCK * CAP / 2);// 6.4 MB
    float*  nsA   = (float*) alloc(NPAD);
    float*  hs0   = (float*) alloc(NPAD);
    float*  ndv   = (float*) alloc(NPAD);
    float*  aggC  = (float*) alloc(NPAD);
    float*  aggA  = (float*) alloc(NPAD);
    float*  aggB  = (float*) alloc(NPAD);
    uint*   aggMn = (uint*)  alloc(NPAD);
    uint*   aggMx = (uint*)  alloc(NPAD);
    float*  U     = (float*) alloc(129 * HIDDEN);
    float*  V     = (float*) alloc(129 * HIDDEN);

    hipMemsetAsync(d_ws, 0, zero_bytes, stream);

    int pblocks = (N_EDGES + PCH - 1) / PCH;    // 391
    int gblocks = NBUCK * SPLIT;                // 1564
    int nblocks = NPAD / 256;                   // 391
    int oblocks = NPAD / 128;                   // 782

    k_part <<<pblocks, PTH, 0, stream>>>(src, dst, bcur1, bcur2, tmp1, tmp2, N_EDGES);
    k_cnt4 <<<gblocks, 256, 0, stream>>>(bcur1, tmp1, bcur2, tmp2, cin, cout);
    k_node1<<<nblocks, 256, 0, stream>>>(cin, cout, W1, b1, W2, nsA, hs0, ndv, aggC, U, V);
    k_agg1 <<<gblocks, 256, 0, stream>>>(bcur1, tmp1, hs0, aggC);
    k_node2<<<nblocks, 256, 0, stream>>>(aggC, nsA, ndv, W1, b1, info, aggA, aggB, aggMn, aggMx);
    k_agg2 <<<gblocks, 256, 0, stream>>>(bcur1, tmp1, info, aggA, aggB, aggMn, aggMx);
    k_pool <<<oblocks, 256, 0, stream>>>(bcur1, tmp1, info, ndv, aggA, aggB, aggMn, aggMx,
                                         U, V, graph_ids, b2, pool, cnt);
    k_final<<<(N_GRAPHS * N_CLASSES + 255) / 256, 256, 0, stream>>>(pool, cnt, Wc, bc, out);
}